// Round 9
// baseline (452.253 us; speedup 1.0000x reference)
//
#include <hip/hip_runtime.h>
#include <hip/hip_bf16.h>
#include <math.h>

typedef __hip_bfloat16 bf16;

#define D_  1024
#define K_  10
#define B_  16384
#define H_  8
#define HD_ 128

struct alignas(16) BF8 { bf16 v[8]; };
struct alignas(8)  BF4 { bf16 v[4]; };

typedef __bf16 bf8v __attribute__((ext_vector_type(8)));
typedef float  f4v  __attribute__((ext_vector_type(4)));

__device__ __forceinline__ float b2f(bf16 x){ return __bfloat162float(x); }
__device__ __forceinline__ bf16  f2b(float x){ return __float2bfloat16(x); }

#define GL2LDS16(g, l) __builtin_amdgcn_global_load_lds( \
    (__attribute__((address_space(1))) void*)(g), \
    (__attribute__((address_space(3))) void*)(l), 16, 0, 0)

// ---------------- row-wise L2 normalize -> bf16 ----------------------------
__global__ __launch_bounds__(256) void l2norm_k(const float* __restrict__ x,
                                                bf16* __restrict__ fnb) {
  int b = blockIdx.x, t = threadIdx.x;
  float4 v = ((const float4*)(x + (size_t)b * D_))[t];
  float p = v.x*v.x + v.y*v.y + v.z*v.z + v.w*v.w;
  #pragma unroll
  for (int o = 32; o > 0; o >>= 1) p += __shfl_down(p, o);
  __shared__ float wsum[4];
  if ((t & 63) == 0) wsum[t >> 6] = p;
  __syncthreads();
  __shared__ float inv_s;
  if (t == 0) inv_s = 1.f / fmaxf(sqrtf(wsum[0]+wsum[1]+wsum[2]+wsum[3]), 1e-8f);
  __syncthreads();
  float iv = inv_s;
  BF4 o;
  o.v[0] = f2b(v.x*iv); o.v[1] = f2b(v.y*iv);
  o.v[2] = f2b(v.z*iv); o.v[3] = f2b(v.w*iv);
  ((BF4*)(fnb + (size_t)b * D_))[t] = o;
}

// ---------------- weight transpose f32[R][C] -> bf16[C][R] -----------------
__global__ __launch_bounds__(256) void wt_k(const float* __restrict__ w,
                                            bf16* __restrict__ wt, int R, int C) {
  __shared__ float tle[32][33];
  int c0 = blockIdx.x * 32, r0 = blockIdx.y * 32;
  int tx = threadIdx.x & 31, ty = threadIdx.x >> 5;
  #pragma unroll
  for (int i = 0; i < 32; i += 8)
    tle[ty + i][tx] = w[(size_t)(r0 + ty + i) * C + c0 + tx];
  __syncthreads();
  #pragma unroll
  for (int i = 0; i < 32; i += 8)
    wt[(size_t)(c0 + ty + i) * R + r0 + tx] = f2b(tle[tx][ty + i]);
}

// ---------------- small panel GEMM: out[10][N] = act(A[10][KD] @ W + b) ----
template<int COLS, int KD, int ACT>
__global__ __launch_bounds__(256) void panelmm_k(
    const float* __restrict__ A, const float* __restrict__ W,
    const float* __restrict__ bias, const float* __restrict__ aux,
    float* __restrict__ out,
    const float* __restrict__ W2, const float* __restrict__ bias2,
    float* __restrict__ out2, int N, int npanel) {
  constexpr int GROUPS = 256 / COLS;
  constexpr int DCH = KD / GROUPS;
  __shared__ float A_s[K_][KD];
  __shared__ float part[K_][COLS][GROUPS];
  const int t = threadIdx.x;
  int blk = blockIdx.x;
  const float* Wm = W; const float* bm = bias; float* om = out;
  if (blk >= npanel) { blk -= npanel; Wm = W2; bm = bias2; om = out2; }
  const int panel = blk;
  for (int i = t; i < K_*KD; i += 256) A_s[0][i] = A[i];
  __syncthreads();
  const int cg = t % COLS, g = t / COLS;
  const int col = panel*COLS + cg;
  float s[K_];
  #pragma unroll
  for (int r = 0; r < K_; ++r) s[r] = 0.f;
  const float* wp = Wm + (size_t)(g*DCH)*N + col;
  for (int d = g*DCH; d < (g+1)*DCH; ++d) {
    float wv = *wp; wp += N;
    #pragma unroll
    for (int r = 0; r < K_; ++r) s[r] = fmaf(A_s[r][d], wv, s[r]);
  }
  #pragma unroll
  for (int r = 0; r < K_; ++r) part[r][cg][g] = s[r];
  __syncthreads();
  for (int o = t; o < K_*COLS; o += 256) {
    int r = o / COLS, c = o % COLS;
    float v = 0.f;
    #pragma unroll
    for (int gg = 0; gg < GROUPS; ++gg) v += part[r][c][gg];
    v += bm[panel*COLS + c];
    if constexpr (ACT == 1) v = fmaxf(v, 0.f);
    if constexpr (ACT == 2) v = aux[(size_t)r*N + panel*COLS + c] + 0.1f*tanhf(v);
    om[(size_t)r*N + panel*COLS + c] = v;
  }
}

// ---------------- small mixed GEMM for W-tilde / V-tilde -------------------
template<int TRANSOUT, typename TW>
__global__ __launch_bounds__(256) void smallmm_k(
    const float* __restrict__ A, const TW* __restrict__ W,
    bf16* __restrict__ outb, float scale) {
  constexpr int COLS = 64, GROUPS = 4, DCH = 32, NW = 1024;
  __shared__ float A_s[K_][128];
  __shared__ float part[K_][COLS][GROUPS];
  const int t = threadIdx.x;
  const int h = blockIdx.x & 7, panel = blockIdx.x >> 3;
  for (int i = t; i < K_*128; i += 256) {
    int r = i >> 7, j = i & 127;
    A_s[r][j] = A[r*1024 + h*128 + j];
  }
  __syncthreads();
  const int cg = t % COLS, g = t / COLS;
  const int col = panel*COLS + cg;
  float s[K_];
  #pragma unroll
  for (int r = 0; r < K_; ++r) s[r] = 0.f;
  const TW* wp = W + (size_t)(h*128 + g*DCH)*NW + col;
  for (int d = g*DCH; d < g*DCH + DCH; ++d) {
    float wv;
    if constexpr (sizeof(TW) == 2) wv = b2f(*wp); else wv = *wp;
    wp += NW;
    #pragma unroll
    for (int r = 0; r < K_; ++r) s[r] = fmaf(A_s[r][d], wv, s[r]);
  }
  #pragma unroll
  for (int r = 0; r < K_; ++r) part[r][cg][g] = s[r];
  __syncthreads();
  for (int o = t; o < 16*COLS; o += 256) {
    int r = o / COLS, c = o % COLS;
    float v = 0.f;
    if (r < K_) {
      #pragma unroll
      for (int gg = 0; gg < GROUPS; ++gg) v += part[r][c][gg];
      v *= scale;
    }
    if constexpr (TRANSOUT) outb[(size_t)(panel*COLS + c)*128 + h*16 + r] = f2b(v);
    else                    outb[(size_t)(h*16 + r)*NW + panel*COLS + c] = f2b(v);
  }
}

// -------- S-bias ext: [0..127] = (q_b_h . K_hk)/sqrt(128); [128+j] = 1+na_j
__global__ void sbias_k(const float* __restrict__ qb, const float* __restrict__ Km,
                        const float* __restrict__ na, float* __restrict__ sb) {
  int c = threadIdx.x;
  if (c < 128) {
    int h = c >> 4, k = c & 15;
    float s = 0.f;
    if (k < K_) {
      for (int j = 0; j < HD_; ++j)
        s = fmaf(qb[h*HD_ + j], Km[(size_t)k*D_ + h*HD_ + j], s);
    }
    sb[c] = s * 0.08838834764831845f;
  } else {
    int j = c - 128;
    sb[c] = (j < K_) ? (1.f + na[j]) : 0.f;
  }
}

// -------- W-tilde ext rows 128..255: row 128+k = -2*an_k (bf16), else 0 ----
__global__ __launch_bounds__(256) void anext_k(const float* __restrict__ an,
                                               bf16* __restrict__ wt) {
  int k = blockIdx.x;                       // 0..127 -> row 128+k
  bf16* dst = wt + (size_t)(128 + k) * 1024;
  int i = threadIdx.x * 4;
  BF4 o;
  if (k < K_) {
    float4 a = *(const float4*)(an + (size_t)k*1024 + i);
    o.v[0] = f2b(-2.f*a.x); o.v[1] = f2b(-2.f*a.y);
    o.v[2] = f2b(-2.f*a.z); o.v[3] = f2b(-2.f*a.w);
  } else {
    o.v[0] = o.v[1] = o.v[2] = o.v[3] = f2b(0.f);
  }
  *(BF4*)(dst + i) = o;
}

// ---------------- ar3: normalize anchors + diversity loss ------------------
__global__ __launch_bounds__(256) void ar3_k(const float* __restrict__ an_un,
    float* __restrict__ an, float* __restrict__ na, float* __restrict__ divloss) {
  __shared__ float a_s[K_][D_];
  __shared__ float nrm[K_];
  __shared__ float dm[45];
  const int t = threadIdx.x;
  for (int i = t; i < K_*D_; i += 256) a_s[0][i] = an_un[i];
  __syncthreads();
  const int wid = t >> 6, lane = t & 63;
  for (int r = wid; r < K_; r += 4) {
    float p = 0.f;
    for (int j = lane; j < D_; j += 64) p += a_s[r][j]*a_s[r][j];
    #pragma unroll
    for (int o = 1; o < 64; o <<= 1) p += __shfl_xor(p, o);
    if (lane == 0) nrm[r] = p;
  }
  __syncthreads();
  for (int i = t; i < K_*D_; i += 256) {
    int r = i >> 10;
    float iv = 1.f / fmaxf(sqrtf(nrm[r]), 1e-8f);
    float v = a_s[0][i] * iv;
    a_s[0][i] = v;
    an[i] = v;
  }
  if (t < K_) {
    float iv = 1.f / fmaxf(sqrtf(nrm[t]), 1e-8f);
    na[t] = nrm[t] * iv * iv;
  }
  __syncthreads();
  const int pr = t >> 2, sub = t & 3;
  if (pr < 45) {
    int i = 0, j = 0, c = pr;
    for (i = 0; i < K_; ++i) { int cnt = K_-1-i; if (c < cnt) { j = i+1+c; break; } c -= cnt; }
    float s = 0.f;
    for (int d = sub*256; d < sub*256 + 256; ++d) {
      float df = a_s[i][d] - a_s[j][d]; s += df*df;
    }
    s += __shfl_xor(s, 1); s += __shfl_xor(s, 2);
    if (sub == 0) dm[pr] = sqrtf(fmaxf(s, 1e-24f));
  }
  __syncthreads();
  if (t == 0) {
    float m = 0.f;
    for (int p = 0; p < 45; ++p) m += dm[p];
    m *= (1.f/45.f);
    *divloss = expf(-fmaxf(m, 1e-6f));
  }
}

// ---------------- 128^2 dbuf swizzled MFMA GEMM ----------------------------
// 256 thr = 4 waves (2x2), wave tile 64x64 (acc = 64 AGPR -> 2-3 blocks/CU),
// BK=32, double-buffered 32 KB LDS, stage-next-before-compute, one
// __syncthreads per K-tile (drain overlapped by co-resident blocks, m114).
// Swizzle: 16B chunk ^= (row>>1)&3 on BOTH stage-source and ds_read ->
// exactly 2-way bank aliasing (free, m136). XCD swizzle on blockIdx.
template<int EPI, typename TO>
__global__ __launch_bounds__(256) void mgemm_k(
    const bf16* __restrict__ A, const bf16* __restrict__ Bt,
    const float* __restrict__ bias, const bf16* __restrict__ aux,
    TO* __restrict__ out, int M, int N, int Kd, float scale) {
  constexpr int BM = 128, BN = 128, BK = 32;
  __shared__ bf16 As[2][BM*BK];   // 2 x 8 KB
  __shared__ bf16 Bs[2][BN*BK];   // 2 x 8 KB -> 32 KB total
  const int tid = threadIdx.x;
  const int nMB = M / BM;
  const int nwg = gridDim.x;
  int wg = blockIdx.x;
  wg = (wg & 7) * (nwg >> 3) + (wg >> 3);   // XCD swizzle (nwg % 8 == 0)
  const int bm = (wg % nMB) * BM, bn = (wg / nMB) * BN;

  // staging: thread covers 16B; row = tid>>2 (+64 for l=1), chunk = tid&3,
  // global source column pre-swizzled by (row>>1)&3 = (tid>>3)&3.
  const int srow = tid >> 2;
  const int ssw  = (((tid & 3) ^ ((tid >> 3) & 3)) * 8);
  const bf16* gA = A  + (size_t)(bm + srow) * Kd + ssw;
  const bf16* gB = Bt + (size_t)(bn + srow) * Kd + ssw;
  const size_t rstep = (size_t)64 * Kd;

  const int w    = tid >> 6;
  const int lane = tid & 63;
  const int wr = (w >> 1) * 64, wc = (w & 1) * 64;
  const int fr = lane & 15, fg = lane >> 4;
  const int key = (fr >> 1) & 3;            // read-side swizzle key

  f4v acc[4][4];
  const f4v zz = {0.f, 0.f, 0.f, 0.f};
  #pragma unroll
  for (int m = 0; m < 4; ++m)
    #pragma unroll
    for (int n = 0; n < 4; ++n) acc[m][n] = zz;

  const int nt = Kd / BK;

  // prologue: stage tile 0 into buf 0
  GL2LDS16(gA,         &As[0][0] + tid*8);
  GL2LDS16(gA + rstep, &As[0][0] + tid*8 + 2048);
  GL2LDS16(gB,         &Bs[0][0] + tid*8);
  GL2LDS16(gB + rstep, &Bs[0][0] + tid*8 + 2048);
  __syncthreads();

  int buf = 0;
  for (int t = 0; t < nt; ++t) {
    if (t + 1 < nt) {                       // stage next tile (flies under MFMA)
      const int ko = (t + 1) * BK;
      GL2LDS16(gA + ko,         &As[buf^1][0] + tid*8);
      GL2LDS16(gA + rstep + ko, &As[buf^1][0] + tid*8 + 2048);
      GL2LDS16(gB + ko,         &Bs[buf^1][0] + tid*8);
      GL2LDS16(gB + rstep + ko, &Bs[buf^1][0] + tid*8 + 2048);
    }
    const bf16* la = &As[buf][0];
    const bf16* lb = &Bs[buf][0];
    bf8v af[4], bq[4];
    #pragma unroll
    for (int m = 0; m < 4; ++m)
      af[m] = *(const bf8v*)(la + (wr + m*16 + fr)*BK + ((fg ^ key) * 8));
    #pragma unroll
    for (int n = 0; n < 4; ++n)
      bq[n] = *(const bf8v*)(lb + (wc + n*16 + fr)*BK + ((fg ^ key) * 8));
    __builtin_amdgcn_s_setprio(1);
    #pragma unroll
    for (int m = 0; m < 4; ++m)
      #pragma unroll
      for (int n = 0; n < 4; ++n)
        acc[m][n] = __builtin_amdgcn_mfma_f32_16x16x32_bf16(af[m], bq[n], acc[m][n], 0, 0, 0);
    __builtin_amdgcn_s_setprio(0);
    __syncthreads();                        // next tile resident after this
    buf ^= 1;
  }

  float bv[4];
  #pragma unroll
  for (int n = 0; n < 4; ++n) bv[n] = bias[bn + wc + n*16 + fr];
  #pragma unroll
  for (int m = 0; m < 4; ++m) {
    #pragma unroll
    for (int r = 0; r < 4; ++r) {
      const int row = bm + wr + m*16 + fg*4 + r;
      #pragma unroll
      for (int n = 0; n < 4; ++n) {
        const int col = bn + wc + n*16 + fr;
        float x = acc[m][n][r] + bv[n];
        if constexpr (EPI == 1) x = b2f(aux[(size_t)row * N + col]) + scale * x;
        if constexpr (EPI == 2) x = 0.5f * x * (1.f + erff(x * 0.70710678118654752f));
        if constexpr (sizeof(TO) == 2) out[(size_t)row * N + col] = f2b(x);
        else                           out[(size_t)row * N + col] = x;
      }
    }
  }
}

// ---------------- attn2: softmax(S) -> aw; center loss from S d2 cols ------
__global__ __launch_bounds__(256) void attn2_k(
    const float* __restrict__ S, bf16* __restrict__ awp,
    float* __restrict__ cen_acc) {
  __shared__ float cred[4];
  const int t = threadIdx.x;
  const int wid = t >> 6, lane = t & 63;
  const int sub = lane & 7, head = lane >> 3;
  const int k0 = sub*2, k1 = k0 + 1;
  float c_acc = 0.f;
  const int row0 = blockIdx.x * 32 + wid * 8;

  for (int i = 0; i < 8; ++i) {
    const int row = row0 + i;
    const float* Sr = S + (size_t)row * 256;
    float2 sv = *(const float2*)(Sr + head*16 + k0);
    float v0 = (k0 < K_) ? sv.x : -1e30f;
    float v1 = (k1 < K_) ? sv.y : -1e30f;
    float m = fmaxf(v0, v1);
    m = fmaxf(m, __shfl_xor(m,1)); m = fmaxf(m, __shfl_xor(m,2)); m = fmaxf(m, __shfl_xor(m,4));
    float e0 = (k0 < K_) ? __expf(v0 - m) : 0.f;
    float e1 = (k1 < K_) ? __expf(v1 - m) : 0.f;
    float es = e0 + e1;
    es += __shfl_xor(es,1); es += __shfl_xor(es,2); es += __shfl_xor(es,4);
    float inv = 1.f / es;
    float a0 = e0 * inv, a1 = e1 * inv;
    bf16 b0 = f2b(a0), b1 = f2b(a1);
    unsigned int pk = (unsigned int)(*(unsigned short*)&b0)
                    | ((unsigned int)(*(unsigned short*)&b1) << 16);
    *(unsigned int*)(awp + (size_t)row*128 + head*16 + k0) = pk;
    float g0 = a0, g1 = a1;
    g0 += __shfl_xor(g0,8); g0 += __shfl_xor(g0,16); g0 += __shfl_xor(g0,32);
    g1 += __shfl_xor(g1,8); g1 += __shfl_xor(g1,16); g1 += __shfl_xor(g1,32);
    if (sub < 5) {
      float d20 = Sr[128 + k0];
      float d21 = Sr[128 + k1];
      c_acc = fmaf(g0, sqrtf(fmaxf(d20, 1e-12f)), c_acc);
      c_acc = fmaf(g1, sqrtf(fmaxf(d21, 1e-12f)), c_acc);
    }
  }
  #pragma unroll
  for (int o = 1; o < 64; o <<= 1) c_acc += __shfl_xor(c_acc, o);
  if (lane == 0) cred[wid] = c_acc;
  __syncthreads();
  if (t == 0) {
    float s = (cred[0]+cred[1]+cred[2]+cred[3]) * (1.f/64.f/(float)B_);
    atomicAdd(cen_acc, s);
  }
}

// ---------------- LayerNorm over rows of bf16 ------------------------------
__global__ __launch_bounds__(256) void ln_k(const bf16* __restrict__ x,
    const float* __restrict__ g, const float* __restrict__ bta,
    bf16* __restrict__ out) {
  int b = blockIdx.x, t = threadIdx.x;
  BF4 ld = ((const BF4*)(x + (size_t)b * D_))[t];
  float v[4];
  #pragma unroll
  for (int j = 0; j < 4; ++j) v[j] = b2f(ld.v[j]);
  float s = v[0]+v[1]+v[2]+v[3];
  #pragma unroll
  for (int o = 32; o > 0; o >>= 1) s += __shfl_down(s, o);
  __shared__ float w1[4], w2[4];
  if ((t & 63) == 0) w1[t >> 6] = s;
  __syncthreads();
  __shared__ float mu_s, rs_s;
  if (t == 0) mu_s = (w1[0]+w1[1]+w1[2]+w1[3]) * (1.f/D_);
  __syncthreads();
  float mu = mu_s;
  float qv = 0.f;
  #pragma unroll
  for (int j = 0; j < 4; ++j) { float d = v[j]-mu; qv += d*d; }
  #pragma unroll
  for (int o = 32; o > 0; o >>= 1) qv += __shfl_down(qv, o);
  if ((t & 63) == 0) w2[t >> 6] = qv;
  __syncthreads();
  if (t == 0) rs_s = rsqrtf((w2[0]+w2[1]+w2[2]+w2[3]) * (1.f/D_) + 1e-5f);
  __syncthreads();
  float rs = rs_s;
  BF4 o;
  #pragma unroll
  for (int j = 0; j < 4; ++j) {
    int col = t*4 + j;
    o.v[j] = f2b((v[j]-mu)*rs*g[col] + bta[col]);
  }
  ((BF4*)(out + (size_t)b * D_))[t] = o;
}

// ---------------- final scalar geo -----------------------------------------
__global__ void geo_k(const float* __restrict__ divl, const float* __restrict__ cen,
                      const float* __restrict__ div_w, const float* __restrict__ cen_w,
                      float* __restrict__ out) {
  float g = fabsf(*div_w) * (*divl) + fabsf(*cen_w) * (*cen);
  out[0] = fminf(fmaxf(g, 0.f), 0.01f);
}

extern "C" void kernel_launch(void* const* d_in, const int* in_sizes, int n_in,
                              void* d_out, int out_size, void* d_ws, size_t ws_size,
                              hipStream_t stream) {
  const float* features = (const float*)d_in[0];
  const float* anchors  = (const float*)d_in[1];
  const float* ar_w1 = (const float*)d_in[2];
  const float* ar_b1 = (const float*)d_in[3];
  const float* ar_w2 = (const float*)d_in[4];
  const float* ar_b2 = (const float*)d_in[5];
  const float* q_w = (const float*)d_in[6];
  const float* q_b = (const float*)d_in[7];
  const float* k_w = (const float*)d_in[8];
  const float* k_b = (const float*)d_in[9];
  const float* v_w = (const float*)d_in[10];
  const float* v_b = (const float*)d_in[11];
  const float* o_w = (const float*)d_in[12];
  const float* o_b = (const float*)d_in[13];
  const float* ln_g = (const float*)d_in[14];
  const float* ln_b = (const float*)d_in[15];
  const float* ff_w1 = (const float*)d_in[16];
  const float* ff_b1 = (const float*)d_in[17];
  const float* ff_w2 = (const float*)d_in[18];
  const float* ff_b2 = (const float*)d_in[19];
  const float* div_w = (const float*)d_in[20];
  const float* cen_w = (const float*)d_in[21];
  float* out = (float*)d_out;

  char* w = (char*)d_ws;
  bf16* ws_fnb = (bf16*)w;  w += (size_t)B_ * D_ * 2;
  bf16* ws_enh = (bf16*)w;  w += (size_t)B_ * D_ * 2;
  bf16* ws_ln  = (bf16*)w;  w += (size_t)B_ * D_ * 2;
  bf16* ws_h   = (bf16*)w;  w += (size_t)B_ * 2048 * 2;
  float* ws_S  = (float*)w; w += (size_t)B_ * 256 * 4;
  bf16* ws_awp = (bf16*)w;  w += (size_t)B_ * 128 * 2;
  bf16* ws_wq  = (bf16*)w;  w += (size_t)D_ * D_ * 2;
  bf16* ws_w1t = (bf16*)w;  w += (size_t)D_ * 2048 * 2;
  bf16* ws_w2t = (bf16*)w;  w += (size_t)2048 * D_ * 2;
  bf16* ws_wt  = (bf16*)w;  w += (size_t)256 * D_ * 2;   // W-tilde ext [256][1024]
  bf16* ws_vt  = (bf16*)w;  w += (size_t)D_ * 128 * 2;   // V-tilde^T [1024][128]
  float* ws_har = (float*)w;  w += (size_t)K_ * (D_/2) * 4;
  float* ws_anu = (float*)w;  w += (size_t)K_ * D_ * 4;
  float* ws_an  = (float*)w;  w += (size_t)K_ * D_ * 4;
  float* ws_k   = (float*)w;  w += (size_t)K_ * D_ * 4;
  float* ws_v   = (float*)w;  w += (size_t)K_ * D_ * 4;
  float* ws_na  = (float*)w;  w += 256;
  float* ws_div = (float*)w;  w += 256;
  float* ws_cen = (float*)w;  w += 256;
  float* ws_sb  = (float*)w;  w += 512;
  if ((size_t)(w - (char*)d_ws) > ws_size) return;

  hipMemsetAsync(ws_cen, 0, 4, stream);

  wt_k<<<dim3(D_/32,   D_/32),   256, 0, stream>>>(q_w,   ws_wq,  D_,   D_);
  wt_k<<<dim3(2048/32, D_/32),   256, 0, stream>>>(ff_w1, ws_w1t, D_,   2048);
  wt_k<<<dim3(D_/32,   2048/32), 256, 0, stream>>>(ff_w2, ws_w2t, 2048, D_);

  l2norm_k<<<B_, 256, 0, stream>>>(features, ws_fnb);

  panelmm_k<32, 1024, 1><<<16, 256, 0, stream>>>(
      anchors, ar_w1, ar_b1, nullptr, ws_har,
      nullptr, nullptr, nullptr, D_/2, 16);
  panelmm_k<64, 512, 2><<<16, 256, 0, stream>>>(
      ws_har, ar_w2, ar_b2, anchors, ws_anu,
      nullptr, nullptr, nullptr, D_, 16);
  ar3_k<<<1, 256, 0, stream>>>(ws_anu, ws_an, ws_na, ws_div);
  panelmm_k<64, 1024, 0><<<32, 256, 0, stream>>>(
      ws_an, k_w, k_b, nullptr, ws_k,
      v_w, v_b, ws_v, D_, 16);

  smallmm_k<0, bf16><<<128, 256, 0, stream>>>(ws_k, ws_wq, ws_wt, 0.08838834764831845f);
  anext_k<<<128, 256, 0, stream>>>(ws_an, ws_wt);
  sbias_k<<<1, 256, 0, stream>>>(q_b, ws_k, ws_na, ws_sb);
  smallmm_k<1, float><<<128, 256, 0, stream>>>(ws_v, o_w, ws_vt, 1.f);

  // S = fn @ [W-tilde | -2an^T] + [sb | 1+na]   [B,256] f32
  mgemm_k<0, float><<<dim3((B_/128)*(256/128)), 256, 0, stream>>>(
      ws_fnb, ws_wt, ws_sb, nullptr, ws_S, B_, 256, D_, 0.f);

  attn2_k<<<B_/32, 256, 0, stream>>>(ws_S, ws_awp, ws_cen);

  // enh = fn + 0.1*(awp @ V-tilde + o_b)
  mgemm_k<1, bf16><<<dim3((B_/128)*(D_/128)), 256, 0, stream>>>(
      ws_awp, ws_vt, o_b, ws_fnb, ws_enh, B_, D_, 128, 0.1f);

  ln_k<<<B_, 256, 0, stream>>>(ws_enh, ln_g, ln_b, ws_ln);

  // h = gelu(ln @ ff_w1 + ff_b1)
  mgemm_k<2, bf16><<<dim3((B_/128)*(2048/128)), 256, 0, stream>>>(
      ws_ln, ws_w1t, ff_b1, nullptr, ws_h, B_, 2048, D_, 0.f);

  // final = fn + 0.2*(h @ ff_w2 + ff_b2) -> d_out (f32)
  mgemm_k<1, float><<<dim3((B_/128)*(D_/128)), 256, 0, stream>>>(
      ws_h, ws_w2t, ff_b2, ws_fnb, out, B_, D_, 2048, 0.2f);

  geo_k<<<1, 1, 0, stream>>>(ws_div, ws_cen, div_w, cen_w, out + (size_t)B_ * D_);
}

// Round 10
// 438.624 us; speedup vs baseline: 1.0311x; 1.0311x over previous
//
#include <hip/hip_runtime.h>
#include <hip/hip_bf16.h>
#include <math.h>

typedef __hip_bfloat16 bf16;

#define D_  1024
#define K_  10
#define B_  16384
#define H_  8
#define HD_ 128

struct alignas(16) BF8 { bf16 v[8]; };
struct alignas(8)  BF4 { bf16 v[4]; };

typedef __bf16 bf8v __attribute__((ext_vector_type(8)));
typedef float  f4v  __attribute__((ext_vector_type(4)));

__device__ __forceinline__ float b2f(bf16 x){ return __bfloat162float(x); }
__device__ __forceinline__ bf16  f2b(float x){ return __float2bfloat16(x); }

#define GL2LDS16(g, l) __builtin_amdgcn_global_load_lds( \
    (__attribute__((address_space(1))) void*)(g), \
    (__attribute__((address_space(3))) void*)(l), 16, 0, 0)

// ---------------- row-wise L2 normalize -> bf16 ----------------------------
__global__ __launch_bounds__(256) void l2norm_k(const float* __restrict__ x,
                                                bf16* __restrict__ fnb) {
  int b = blockIdx.x, t = threadIdx.x;
  float4 v = ((const float4*)(x + (size_t)b * D_))[t];
  float p = v.x*v.x + v.y*v.y + v.z*v.z + v.w*v.w;
  #pragma unroll
  for (int o = 32; o > 0; o >>= 1) p += __shfl_down(p, o);
  __shared__ float wsum[4];
  if ((t & 63) == 0) wsum[t >> 6] = p;
  __syncthreads();
  __shared__ float inv_s;
  if (t == 0) inv_s = 1.f / fmaxf(sqrtf(wsum[0]+wsum[1]+wsum[2]+wsum[3]), 1e-8f);
  __syncthreads();
  float iv = inv_s;
  BF4 o;
  o.v[0] = f2b(v.x*iv); o.v[1] = f2b(v.y*iv);
  o.v[2] = f2b(v.z*iv); o.v[3] = f2b(v.w*iv);
  ((BF4*)(fnb + (size_t)b * D_))[t] = o;
}

// ---------------- weight transpose f32[R][C] -> bf16[C][R] -----------------
__global__ __launch_bounds__(256) void wt_k(const float* __restrict__ w,
                                            bf16* __restrict__ wt, int R, int C) {
  __shared__ float tle[32][33];
  int c0 = blockIdx.x * 32, r0 = blockIdx.y * 32;
  int tx = threadIdx.x & 31, ty = threadIdx.x >> 5;
  #pragma unroll
  for (int i = 0; i < 32; i += 8)
    tle[ty + i][tx] = w[(size_t)(r0 + ty + i) * C + c0 + tx];
  __syncthreads();
  #pragma unroll
  for (int i = 0; i < 32; i += 8)
    wt[(size_t)(c0 + ty + i) * R + r0 + tx] = f2b(tle[tx][ty + i]);
}

// ---------------- small panel GEMM: out[10][N] = act(A[10][KD] @ W + b) ----
template<int COLS, int KD, int ACT>
__global__ __launch_bounds__(256) void panelmm_k(
    const float* __restrict__ A, const float* __restrict__ W,
    const float* __restrict__ bias, const float* __restrict__ aux,
    float* __restrict__ out,
    const float* __restrict__ W2, const float* __restrict__ bias2,
    float* __restrict__ out2, int N, int npanel) {
  constexpr int GROUPS = 256 / COLS;
  constexpr int DCH = KD / GROUPS;
  __shared__ float A_s[K_][KD];
  __shared__ float part[K_][COLS][GROUPS];
  const int t = threadIdx.x;
  int blk = blockIdx.x;
  const float* Wm = W; const float* bm = bias; float* om = out;
  if (blk >= npanel) { blk -= npanel; Wm = W2; bm = bias2; om = out2; }
  const int panel = blk;
  for (int i = t; i < K_*KD; i += 256) A_s[0][i] = A[i];
  __syncthreads();
  const int cg = t % COLS, g = t / COLS;
  const int col = panel*COLS + cg;
  float s[K_];
  #pragma unroll
  for (int r = 0; r < K_; ++r) s[r] = 0.f;
  const float* wp = Wm + (size_t)(g*DCH)*N + col;
  for (int d = g*DCH; d < (g+1)*DCH; ++d) {
    float wv = *wp; wp += N;
    #pragma unroll
    for (int r = 0; r < K_; ++r) s[r] = fmaf(A_s[r][d], wv, s[r]);
  }
  #pragma unroll
  for (int r = 0; r < K_; ++r) part[r][cg][g] = s[r];
  __syncthreads();
  for (int o = t; o < K_*COLS; o += 256) {
    int r = o / COLS, c = o % COLS;
    float v = 0.f;
    #pragma unroll
    for (int gg = 0; gg < GROUPS; ++gg) v += part[r][c][gg];
    v += bm[panel*COLS + c];
    if constexpr (ACT == 1) v = fmaxf(v, 0.f);
    if constexpr (ACT == 2) v = aux[(size_t)r*N + panel*COLS + c] + 0.1f*tanhf(v);
    om[(size_t)r*N + panel*COLS + c] = v;
  }
}

// ---------------- small mixed GEMM for W-tilde / V-tilde -------------------
template<int TRANSOUT, typename TW>
__global__ __launch_bounds__(256) void smallmm_k(
    const float* __restrict__ A, const TW* __restrict__ W,
    bf16* __restrict__ outb, float scale) {
  constexpr int COLS = 64, GROUPS = 4, DCH = 32, NW = 1024;
  __shared__ float A_s[K_][128];
  __shared__ float part[K_][COLS][GROUPS];
  const int t = threadIdx.x;
  const int h = blockIdx.x & 7, panel = blockIdx.x >> 3;
  for (int i = t; i < K_*128; i += 256) {
    int r = i >> 7, j = i & 127;
    A_s[r][j] = A[r*1024 + h*128 + j];
  }
  __syncthreads();
  const int cg = t % COLS, g = t / COLS;
  const int col = panel*COLS + cg;
  float s[K_];
  #pragma unroll
  for (int r = 0; r < K_; ++r) s[r] = 0.f;
  const TW* wp = W + (size_t)(h*128 + g*DCH)*NW + col;
  for (int d = g*DCH; d < g*DCH + DCH; ++d) {
    float wv;
    if constexpr (sizeof(TW) == 2) wv = b2f(*wp); else wv = *wp;
    wp += NW;
    #pragma unroll
    for (int r = 0; r < K_; ++r) s[r] = fmaf(A_s[r][d], wv, s[r]);
  }
  #pragma unroll
  for (int r = 0; r < K_; ++r) part[r][cg][g] = s[r];
  __syncthreads();
  for (int o = t; o < 16*COLS; o += 256) {
    int r = o / COLS, c = o % COLS;
    float v = 0.f;
    if (r < K_) {
      #pragma unroll
      for (int gg = 0; gg < GROUPS; ++gg) v += part[r][c][gg];
      v *= scale;
    }
    if constexpr (TRANSOUT) outb[(size_t)(panel*COLS + c)*128 + h*16 + r] = f2b(v);
    else                    outb[(size_t)(h*16 + r)*NW + panel*COLS + c] = f2b(v);
  }
}

// -------- S-bias ext: [0..127] = (q_b_h . K_hk)/sqrt(128); [128+j] = 1+na_j
__global__ void sbias_k(const float* __restrict__ qb, const float* __restrict__ Km,
                        const float* __restrict__ na, float* __restrict__ sb) {
  int c = threadIdx.x;
  if (c < 128) {
    int h = c >> 4, k = c & 15;
    float s = 0.f;
    if (k < K_) {
      for (int j = 0; j < HD_; ++j)
        s = fmaf(qb[h*HD_ + j], Km[(size_t)k*D_ + h*HD_ + j], s);
    }
    sb[c] = s * 0.08838834764831845f;
  } else {
    int j = c - 128;
    sb[c] = (j < K_) ? (1.f + na[j]) : 0.f;
  }
}

// -------- W-tilde ext rows 128..255: row 128+k = -2*an_k (bf16), else 0 ----
__global__ __launch_bounds__(256) void anext_k(const float* __restrict__ an,
                                               bf16* __restrict__ wt) {
  int k = blockIdx.x;
  bf16* dst = wt + (size_t)(128 + k) * 1024;
  int i = threadIdx.x * 4;
  BF4 o;
  if (k < K_) {
    float4 a = *(const float4*)(an + (size_t)k*1024 + i);
    o.v[0] = f2b(-2.f*a.x); o.v[1] = f2b(-2.f*a.y);
    o.v[2] = f2b(-2.f*a.z); o.v[3] = f2b(-2.f*a.w);
  } else {
    o.v[0] = o.v[1] = o.v[2] = o.v[3] = f2b(0.f);
  }
  *(BF4*)(dst + i) = o;
}

// ---------------- ar3: normalize anchors + diversity loss ------------------
__global__ __launch_bounds__(256) void ar3_k(const float* __restrict__ an_un,
    float* __restrict__ an, float* __restrict__ na, float* __restrict__ divloss) {
  __shared__ float a_s[K_][D_];
  __shared__ float nrm[K_];
  __shared__ float dm[45];
  const int t = threadIdx.x;
  for (int i = t; i < K_*D_; i += 256) a_s[0][i] = an_un[i];
  __syncthreads();
  const int wid = t >> 6, lane = t & 63;
  for (int r = wid; r < K_; r += 4) {
    float p = 0.f;
    for (int j = lane; j < D_; j += 64) p += a_s[r][j]*a_s[r][j];
    #pragma unroll
    for (int o = 1; o < 64; o <<= 1) p += __shfl_xor(p, o);
    if (lane == 0) nrm[r] = p;
  }
  __syncthreads();
  for (int i = t; i < K_*D_; i += 256) {
    int r = i >> 10;
    float iv = 1.f / fmaxf(sqrtf(nrm[r]), 1e-8f);
    float v = a_s[0][i] * iv;
    a_s[0][i] = v;
    an[i] = v;
  }
  if (t < K_) {
    float iv = 1.f / fmaxf(sqrtf(nrm[t]), 1e-8f);
    na[t] = nrm[t] * iv * iv;
  }
  __syncthreads();
  const int pr = t >> 2, sub = t & 3;
  if (pr < 45) {
    int i = 0, j = 0, c = pr;
    for (i = 0; i < K_; ++i) { int cnt = K_-1-i; if (c < cnt) { j = i+1+c; break; } c -= cnt; }
    float s = 0.f;
    for (int d = sub*256; d < sub*256 + 256; ++d) {
      float df = a_s[i][d] - a_s[j][d]; s += df*df;
    }
    s += __shfl_xor(s, 1); s += __shfl_xor(s, 2);
    if (sub == 0) dm[pr] = sqrtf(fmaxf(s, 1e-24f));
  }
  __syncthreads();
  if (t == 0) {
    float m = 0.f;
    for (int p = 0; p < 45; ++p) m += dm[p];
    m *= (1.f/45.f);
    *divloss = expf(-fmaxf(m, 1e-6f));
  }
}

// ---------------- 128^2 dbuf swizzled MFMA GEMM (S-GEMM, enh-GEMM) ---------
template<int EPI, typename TO>
__global__ __launch_bounds__(256) void mgemm_k(
    const bf16* __restrict__ A, const bf16* __restrict__ Bt,
    const float* __restrict__ bias, const bf16* __restrict__ aux,
    TO* __restrict__ out, int M, int N, int Kd, float scale) {
  constexpr int BM = 128, BN = 128, BK = 32;
  __shared__ bf16 As[2][BM*BK];
  __shared__ bf16 Bs[2][BN*BK];
  const int tid = threadIdx.x;
  const int nMB = M / BM;
  const int nwg = gridDim.x;
  int wg = blockIdx.x;
  wg = (wg & 7) * (nwg >> 3) + (wg >> 3);
  const int bm = (wg % nMB) * BM, bn = (wg / nMB) * BN;

  const int srow = tid >> 2;
  const int ssw  = (((tid & 3) ^ ((tid >> 3) & 3)) * 8);
  const bf16* gA = A  + (size_t)(bm + srow) * Kd + ssw;
  const bf16* gB = Bt + (size_t)(bn + srow) * Kd + ssw;
  const size_t rstep = (size_t)64 * Kd;

  const int w    = tid >> 6;
  const int lane = tid & 63;
  const int wr = (w >> 1) * 64, wc = (w & 1) * 64;
  const int fr = lane & 15, fg = lane >> 4;
  const int key = (fr >> 1) & 3;

  f4v acc[4][4];
  const f4v zz = {0.f, 0.f, 0.f, 0.f};
  #pragma unroll
  for (int m = 0; m < 4; ++m)
    #pragma unroll
    for (int n = 0; n < 4; ++n) acc[m][n] = zz;

  const int nt = Kd / BK;

  GL2LDS16(gA,         &As[0][0] + tid*8);
  GL2LDS16(gA + rstep, &As[0][0] + tid*8 + 2048);
  GL2LDS16(gB,         &Bs[0][0] + tid*8);
  GL2LDS16(gB + rstep, &Bs[0][0] + tid*8 + 2048);
  __syncthreads();

  int buf = 0;
  for (int t = 0; t < nt; ++t) {
    if (t + 1 < nt) {
      const int ko = (t + 1) * BK;
      GL2LDS16(gA + ko,         &As[buf^1][0] + tid*8);
      GL2LDS16(gA + rstep + ko, &As[buf^1][0] + tid*8 + 2048);
      GL2LDS16(gB + ko,         &Bs[buf^1][0] + tid*8);
      GL2LDS16(gB + rstep + ko, &Bs[buf^1][0] + tid*8 + 2048);
    }
    const bf16* la = &As[buf][0];
    const bf16* lb = &Bs[buf][0];
    bf8v af[4], bq[4];
    #pragma unroll
    for (int m = 0; m < 4; ++m)
      af[m] = *(const bf8v*)(la + (wr + m*16 + fr)*BK + ((fg ^ key) * 8));
    #pragma unroll
    for (int n = 0; n < 4; ++n)
      bq[n] = *(const bf8v*)(lb + (wc + n*16 + fr)*BK + ((fg ^ key) * 8));
    __builtin_amdgcn_s_setprio(1);
    #pragma unroll
    for (int m = 0; m < 4; ++m)
      #pragma unroll
      for (int n = 0; n < 4; ++n)
        acc[m][n] = __builtin_amdgcn_mfma_f32_16x16x32_bf16(af[m], bq[n], acc[m][n], 0, 0, 0);
    __builtin_amdgcn_s_setprio(0);
    __syncthreads();
    buf ^= 1;
  }

  float bv[4];
  #pragma unroll
  for (int n = 0; n < 4; ++n) bv[n] = bias[bn + wc + n*16 + fr];
  #pragma unroll
  for (int m = 0; m < 4; ++m) {
    #pragma unroll
    for (int r = 0; r < 4; ++r) {
      const int row = bm + wr + m*16 + fg*4 + r;
      #pragma unroll
      for (int n = 0; n < 4; ++n) {
        const int col = bn + wc + n*16 + fr;
        float x = acc[m][n][r] + bv[n];
        if constexpr (EPI == 1) x = b2f(aux[(size_t)row * N + col]) + scale * x;
        if constexpr (EPI == 2) x = 0.5f * x * (1.f + erff(x * 0.70710678118654752f));
        if constexpr (sizeof(TO) == 2) out[(size_t)row * N + col] = f2b(x);
        else                           out[(size_t)row * N + col] = x;
      }
    }
  }
}

// ---------------- 256^2 8-phase MFMA GEMM (T1+T2+T3+T4+T5) -----------------
// LDS halves are K-HALVES: As/Bs[2 dbuf][2 kk][256 rows x 32 k]. K-tile = 4
// phases: {kk0 x m0-3, kk0 x m4-7, kk1 x m0-3, kk1 x m4-7}, 16 MFMA each.
// Stage schedule (1 half/phase): P1 A-k1(t+1), P2 B-k1(t+1) (region freed at
// end of tile t-1); P3 A-k0(t+2), P4 B-k0(t+2) (region freed at P2 barrier).
// vmcnt(4) at tile end = 2 newest halves may fly (never drain; T4).
// lgkmcnt(0)+fence before every barrier: reads of a freed region retire
// before any wave can issue its overwriting stage. Requires nt >= 3.
#define FENCE8 asm volatile("" ::: "memory")
#define BAR8 do { asm volatile("s_waitcnt lgkmcnt(0)" ::: "memory"); \
                  __builtin_amdgcn_s_barrier(); FENCE8; } while(0)

template<int EPI, typename TO>
__global__ __launch_bounds__(512) void mgemm256_k(
    const bf16* __restrict__ A, const bf16* __restrict__ Bt,
    const float* __restrict__ bias, const bf16* __restrict__ aux,
    TO* __restrict__ out, int M, int N, int Kd, float scale) {
  constexpr int BM = 256, BN = 256;
  __shared__ bf16 As[2][2][256*32];   // [dbuf][kk-half][row*32+k] 4x16KB
  __shared__ bf16 Bs[2][2][256*32];   // total 128 KB
  const int tid = threadIdx.x;
  const int nMB = M / BM;
  const int nwg = gridDim.x;
  int wg = blockIdx.x;
  wg = (wg & 7) * (nwg >> 3) + (wg >> 3);   // XCD swizzle (nwg % 8 == 0)
  const int bm = (wg % nMB) * BM, bn = (wg / nMB) * BN;

  // staging: half-tile = 256 rows x 32 k = 1024 slots of 16B; 2 loads/thread.
  // slot = l*512+tid -> row = slot>>2 (l=1 -> +128), chunk = slot&3.
  // swizzle chunk ^= (row>>1)&3 on the GLOBAL source (LDS linear).
  const int sr0 = tid >> 2;
  const int sc0 = (((tid & 3) ^ ((sr0 >> 1) & 3)) * 8);  // same for l=1 (row+128)
  const bf16* gA = A  + (size_t)(bm + sr0) * Kd + sc0;
  const bf16* gB = Bt + (size_t)(bn + sr0) * Kd + sc0;
  const size_t rstep = (size_t)128 * Kd;

#define STG_A(bu, kkh, kt) do { \
    GL2LDS16(gA + (kt)*64 + (kkh)*32,         &As[bu][kkh][0] + tid*8); \
    GL2LDS16(gA + rstep + (kt)*64 + (kkh)*32, &As[bu][kkh][0] + tid*8 + 4096); \
  } while(0)
#define STG_B(bu, kkh, kt) do { \
    GL2LDS16(gB + (kt)*64 + (kkh)*32,         &Bs[bu][kkh][0] + tid*8); \
    GL2LDS16(gB + rstep + (kt)*64 + (kkh)*32, &Bs[bu][kkh][0] + tid*8 + 4096); \
  } while(0)

  const int wid = tid >> 6, lane = tid & 63;
  const int wm = wid >> 2, wn = wid & 3;    // 2M x 4N waves; tile 128x64
  const int fr = lane & 15, fg = lane >> 4; // fg 0..3 = k-chunk in 32-wide half
  const int key = (fr >> 1) & 3;
  const int co  = ((fg ^ key) * 8);
  const int aoff0 = (wm*128 + fr) * 32 + co;  // + m*512
  const int boff0 = (wn*64  + fr) * 32 + co;  // + n*512

  f4v acc[8][4];
  const f4v zz = {0.f, 0.f, 0.f, 0.f};
  #pragma unroll
  for (int m = 0; m < 8; ++m)
    #pragma unroll
    for (int n = 0; n < 4; ++n) acc[m][n] = zz;

  const int nt = Kd / 64;   // requires nt >= 3

  // prologue: tile0 all 4 halves + tile1 kk0 halves (ages match steady state)
  STG_A(0,0,0); STG_B(0,0,0); STG_A(0,1,0); STG_B(0,1,0);
  STG_A(1,0,1); STG_B(1,0,1);
  asm volatile("s_waitcnt vmcnt(4)" ::: "memory");
  BAR8;

  for (int t = 0; t < nt; ++t) {
    const int buf = t & 1, nbuf = buf ^ 1;
    const bf16* a0p = &As[buf][0][0];
    const bf16* b0p = &Bs[buf][0][0];
    const bf16* a1p = &As[buf][1][0];
    const bf16* b1p = &Bs[buf][1][0];
    bf8v bq[4], af[4];
    // ---- P1: kk0, m0-3 ----
    if (t + 1 < nt) STG_A(nbuf, 1, t+1);
    #pragma unroll
    for (int n = 0; n < 4; ++n) bq[n] = *(const bf8v*)(b0p + boff0 + n*512);
    #pragma unroll
    for (int m = 0; m < 4; ++m) af[m] = *(const bf8v*)(a0p + aoff0 + m*512);
    __builtin_amdgcn_s_setprio(1);
    #pragma unroll
    for (int m = 0; m < 4; ++m)
      #pragma unroll
      for (int n = 0; n < 4; ++n)
        acc[m][n] = __builtin_amdgcn_mfma_f32_16x16x32_bf16(af[m], bq[n], acc[m][n], 0, 0, 0);
    __builtin_amdgcn_s_setprio(0);
    BAR8;
    // ---- P2: kk0, m4-7 ----
    if (t + 1 < nt) STG_B(nbuf, 1, t+1);
    #pragma unroll
    for (int m = 0; m < 4; ++m) af[m] = *(const bf8v*)(a0p + aoff0 + (m+4)*512);
    __builtin_amdgcn_s_setprio(1);
    #pragma unroll
    for (int m = 0; m < 4; ++m)
      #pragma unroll
      for (int n = 0; n < 4; ++n)
        acc[m+4][n] = __builtin_amdgcn_mfma_f32_16x16x32_bf16(af[m], bq[n], acc[m+4][n], 0, 0, 0);
    __builtin_amdgcn_s_setprio(0);
    BAR8;                                   // kk0 regions of buf now free
    // ---- P3: kk1, m0-3 ----
    if (t + 2 < nt) STG_A(buf, 0, t+2);
    #pragma unroll
    for (int n = 0; n < 4; ++n) bq[n] = *(const bf8v*)(b1p + boff0 + n*512);
    #pragma unroll
    for (int m = 0; m < 4; ++m) af[m] = *(const bf8v*)(a1p + aoff0 + m*512);
    __builtin_amdgcn_s_setprio(1);
    #pragma unroll
    for (int m = 0; m < 4; ++m)
      #pragma unroll
      for (int n = 0; n < 4; ++n)
        acc[m][n] = __builtin_amdgcn_mfma_f32_16x16x32_bf16(af[m], bq[n], acc[m][n], 0, 0, 0);
    __builtin_amdgcn_s_setprio(0);
    BAR8;
    // ---- P4: kk1, m4-7 ----
    if (t + 2 < nt) STG_B(buf, 0, t+2);
    #pragma unroll
    for (int m = 0; m < 4; ++m) af[m] = *(const bf8v*)(a1p + aoff0 + (m+4)*512);
    __builtin_amdgcn_s_setprio(1);
    #pragma unroll
    for (int m = 0; m < 4; ++m)
      #pragma unroll
      for (int n = 0; n < 4; ++n)
        acc[m+4][n] = __builtin_amdgcn_mfma_f32_16x16x32_bf16(af[m], bq[n], acc[m+4][n], 0, 0, 0);
    __builtin_amdgcn_s_setprio(0);
    if (t < nt - 2) asm volatile("s_waitcnt vmcnt(4)" ::: "memory");
    else            asm volatile("s_waitcnt vmcnt(0)" ::: "memory");
    BAR8;
  }

  float bv[4];
  #pragma unroll
  for (int n = 0; n < 4; ++n) bv[n] = bias[bn + wn*64 + n*16 + fr];
  #pragma unroll
  for (int m = 0; m < 8; ++m) {
    #pragma unroll
    for (int r = 0; r < 4; ++r) {
      const int row = bm + wm*128 + m*16 + fg*4 + r;
      #pragma unroll
      for (int n = 0; n < 4; ++n) {
        const int col = bn + wn*64 + n*16 + fr;
        float x = acc[m][n][r] + bv[n];
        if constexpr (EPI == 1) x = b2f(aux[(size_t)row * N + col]) + scale * x;
        if constexpr (EPI == 2) x = 0.5f * x * (1.f + erff(x * 0.70710678118654752f));
        if constexpr (sizeof(TO) == 2) out[(size_t)row * N + col] = f2b(x);
        else                           out[(size_t)row * N + col] = x;
      }
    }
  }
#undef STG_A
#undef STG_B
}

// ---------------- attn2: softmax(S) -> aw; center loss from S d2 cols ------
__global__ __launch_bounds__(256) void attn2_k(
    const float* __restrict__ S, bf16* __restrict__ awp,
    float* __restrict__ cen_acc) {
  __shared__ float cred[4];
  const int t = threadIdx.x;
  const int wid = t >> 6, lane = t & 63;
  const int sub = lane & 7, head = lane >> 3;
  const int k0 = sub*2, k1 = k0 + 1;
  float c_acc = 0.f;
  const int row0 = blockIdx.x * 32 + wid * 8;

  for (int i = 0; i < 8; ++i) {
    const int row = row0 + i;
    const float* Sr = S + (size_t)row * 256;
    float2 sv = *(const float2*)(Sr + head*16 + k0);
    float v0 = (k0 < K_) ? sv.x : -1e30f;
    float v1 = (k1 < K_) ? sv.y : -1e30f;
    float m = fmaxf(v0, v1);
    m = fmaxf(m, __shfl_xor(m,1)); m = fmaxf(m, __shfl_xor(m,2)); m = fmaxf(m, __shfl_xor(m,4));
    float e0 = (k0 < K_) ? __expf(v0 - m) : 0.f;
    float e1 = (k1 < K_) ? __expf(v1 - m) : 0.f;
    float es = e0 + e1;
    es += __shfl_xor(es,1); es += __shfl_xor(es,2); es += __shfl_xor(es,4);
    float inv = 1.f / es;
    float a0 = e0 * inv, a1 = e1 * inv;
    bf16 b0 = f2b(a0), b1 = f2b(a1);
    unsigned int pk = (unsigned int)(*(unsigned short*)&b0)
                    | ((unsigned int)(*(unsigned short*)&b1) << 16);
    *(unsigned int*)(awp + (size_t)row*128 + head*16 + k0) = pk;
    float g0 = a0, g1 = a1;
    g0 += __shfl_xor(g0,8); g0 += __shfl_xor(g0,16); g0 += __shfl_xor(g0,32);
    g1 += __shfl_xor(g1,8); g1 += __shfl_xor(g1,16); g1 += __shfl_xor(g1,32);
    if (sub < 5) {
      float d20 = Sr[128 + k0];
      float d21 = Sr[128 + k1];
      c_acc = fmaf(g0, sqrtf(fmaxf(d20, 1e-12f)), c_acc);
      c_acc = fmaf(g1, sqrtf(fmaxf(d21, 1e-12f)), c_acc);
    }
  }
  #pragma unroll
  for (int o = 1; o < 64; o <<= 1) c_acc += __shfl_xor(c_acc, o);
  if (lane == 0) cred[wid] = c_acc;
  __syncthreads();
  if (t == 0) {
    float s = (cred[0]+cred[1]+cred[2]+cred[3]) * (1.f/64.f/(float)B_);
    atomicAdd(cen_acc, s);
  }
}

// ---------------- LayerNorm over rows of bf16 ------------------------------
__global__ __launch_bounds__(256) void ln_k(const bf16* __restrict__ x,
    const float* __restrict__ g, const float* __restrict__ bta,
    bf16* __restrict__ out) {
  int b = blockIdx.x, t = threadIdx.x;
  BF4 ld = ((const BF4*)(x + (size_t)b * D_))[t];
  float v[4];
  #pragma unroll
  for (int j = 0; j < 4; ++j) v[j] = b2f(ld.v[j]);
  float s = v[0]+v[1]+v[2]+v[3];
  #pragma unroll
  for (int o = 32; o > 0; o >>= 1) s += __shfl_down(s, o);
  __shared__ float w1[4], w2[4];
  if ((t & 63) == 0) w1[t >> 6] = s;
  __syncthreads();
  __shared__ float mu_s, rs_s;
  if (t == 0) mu_s = (w1[0]+w1[1]+w1[2]+w1[3]) * (1.f/D_);
  __syncthreads();
  float mu = mu_s;
  float qv = 0.f;
  #pragma unroll
  for (int j = 0; j < 4; ++j) { float d = v[j]-mu; qv += d*d; }
  #pragma unroll
  for (int o = 32; o > 0; o >>= 1) qv += __shfl_down(qv, o);
  if ((t & 63) == 0) w2[t >> 6] = qv;
  __syncthreads();
  if (t == 0) rs_s = rsqrtf((w2[0]+w2[1]+w2[2]+w2[3]) * (1.f/D_) + 1e-5f);
  __syncthreads();
  float rs = rs_s;
  BF4 o;
  #pragma unroll
  for (int j = 0; j < 4; ++j) {
    int col = t*4 + j;
    o.v[j] = f2b((v[j]-mu)*rs*g[col] + bta[col]);
  }
  ((BF4*)(out + (size_t)b * D_))[t] = o;
}

// ---------------- final scalar geo -----------------------------------------
__global__ void geo_k(const float* __restrict__ divl, const float* __restrict__ cen,
                      const float* __restrict__ div_w, const float* __restrict__ cen_w,
                      float* __restrict__ out) {
  float g = fabsf(*div_w) * (*divl) + fabsf(*cen_w) * (*cen);
  out[0] = fminf(fmaxf(g, 0.f), 0.01f);
}

extern "C" void kernel_launch(void* const* d_in, const int* in_sizes, int n_in,
                              void* d_out, int out_size, void* d_ws, size_t ws_size,
                              hipStream_t stream) {
  const float* features = (const float*)d_in[0];
  const float* anchors  = (const float*)d_in[1];
  const float* ar_w1 = (const float*)d_in[2];
  const float* ar_b1 = (const float*)d_in[3];
  const float* ar_w2 = (const float*)d_in[4];
  const float* ar_b2 = (const float*)d_in[5];
  const float* q_w = (const float*)d_in[6];
  const float* q_b = (const float*)d_in[7];
  const float* k_w = (const float*)d_in[8];
  const float* k_b = (const float*)d_in[9];
  const float* v_w = (const float*)d_in[10];
  const float* v_b = (const float*)d_in[11];
  const float* o_w = (const float*)d_in[12];
  const float* o_b = (const float*)d_in[13];
  const float* ln_g = (const float*)d_in[14];
  const float* ln_b = (const float*)d_in[15];
  const float* ff_w1 = (const float*)d_in[16];
  const float* ff_b1 = (const float*)d_in[17];
  const float* ff_w2 = (const float*)d_in[18];
  const float* ff_b2 = (const float*)d_in[19];
  const float* div_w = (const float*)d_in[20];
  const float* cen_w = (const float*)d_in[21];
  float* out = (float*)d_out;

  char* w = (char*)d_ws;
  bf16* ws_fnb = (bf16*)w;  w += (size_t)B_ * D_ * 2;
  bf16* ws_enh = (bf16*)w;  w += (size_t)B_ * D_ * 2;
  bf16* ws_ln  = (bf16*)w;  w += (size_t)B_ * D_ * 2;
  bf16* ws_h   = (bf16*)w;  w += (size_t)B_ * 2048 * 2;
  float* ws_S  = (float*)w; w += (size_t)B_ * 256 * 4;
  bf16* ws_awp = (bf16*)w;  w += (size_t)B_ * 128 * 2;
  bf16* ws_wq  = (bf16*)w;  w += (size_t)D_ * D_ * 2;
  bf16* ws_w1t = (bf16*)w;  w += (size_t)D_ * 2048 * 2;
  bf16* ws_w2t = (bf16*)w;  w += (size_t)2048 * D_ * 2;
  bf16* ws_wt  = (bf16*)w;  w += (size_t)256 * D_ * 2;
  bf16* ws_vt  = (bf16*)w;  w += (size_t)D_ * 128 * 2;
  float* ws_har = (float*)w;  w += (size_t)K_ * (D_/2) * 4;
  float* ws_anu = (float*)w;  w += (size_t)K_ * D_ * 4;
  float* ws_an  = (float*)w;  w += (size_t)K_ * D_ * 4;
  float* ws_k   = (float*)w;  w += (size_t)K_ * D_ * 4;
  float* ws_v   = (float*)w;  w += (size_t)K_ * D_ * 4;
  float* ws_na  = (float*)w;  w += 256;
  float* ws_div = (float*)w;  w += 256;
  float* ws_cen = (float*)w;  w += 256;
  float* ws_sb  = (float*)w;  w += 512;
  if ((size_t)(w - (char*)d_ws) > ws_size) return;

  hipMemsetAsync(ws_cen, 0, 4, stream);

  wt_k<<<dim3(D_/32,   D_/32),   256, 0, stream>>>(q_w,   ws_wq,  D_,   D_);
  wt_k<<<dim3(2048/32, D_/32),   256, 0, stream>>>(ff_w1, ws_w1t, D_,   2048);
  wt_k<<<dim3(D_/32,   2048/32), 256, 0, stream>>>(ff_w2, ws_w2t, 2048, D_);

  l2norm_k<<<B_, 256, 0, stream>>>(features, ws_fnb);

  panelmm_k<32, 1024, 1><<<16, 256, 0, stream>>>(
      anchors, ar_w1, ar_b1, nullptr, ws_har,
      nullptr, nullptr, nullptr, D_/2, 16);
  panelmm_k<64, 512, 2><<<16, 256, 0, stream>>>(
      ws_har, ar_w2, ar_b2, anchors, ws_anu,
      nullptr, nullptr, nullptr, D_, 16);
  ar3_k<<<1, 256, 0, stream>>>(ws_anu, ws_an, ws_na, ws_div);
  panelmm_k<64, 1024, 0><<<32, 256, 0, stream>>>(
      ws_an, k_w, k_b, nullptr, ws_k,
      v_w, v_b, ws_v, D_, 16);

  smallmm_k<0, bf16><<<128, 256, 0, stream>>>(ws_k, ws_wq, ws_wt, 0.08838834764831845f);
  anext_k<<<128, 256, 0, stream>>>(ws_an, ws_wt);
  sbias_k<<<1, 256, 0, stream>>>(q_b, ws_k, ws_na, ws_sb);
  smallmm_k<1, float><<<128, 256, 0, stream>>>(ws_v, o_w, ws_vt, 1.f);

  // S = fn @ [W-tilde | -2an^T] + [sb | 1+na]   [B,256] f32  (128^2 kernel)
  mgemm_k<0, float><<<dim3((B_/128)*(256/128)), 256, 0, stream>>>(
      ws_fnb, ws_wt, ws_sb, nullptr, ws_S, B_, 256, D_, 0.f);

  attn2_k<<<B_/32, 256, 0, stream>>>(ws_S, ws_awp, ws_cen);

  // enh = fn + 0.1*(awp @ V-tilde + o_b)  (K=128 -> 128^2 kernel)
  mgemm_k<1, bf16><<<dim3((B_/128)*(D_/128)), 256, 0, stream>>>(
      ws_awp, ws_vt, o_b, ws_fnb, ws_enh, B_, D_, 128, 0.1f);

  ln_k<<<B_, 256, 0, stream>>>(ws_enh, ln_g, ln_b, ws_ln);

  // h = gelu(ln @ ff_w1 + ff_b1)   (8-phase 256^2, nt=16)
  mgemm256_k<2, bf16><<<dim3((B_/256)*(2048/256)), 512, 0, stream>>>(
      ws_ln, ws_w1t, ff_b1, nullptr, ws_h, B_, 2048, D_, 0.f);

  // final = fn + 0.2*(h @ ff_w2 + ff_b2) -> d_out (f32)   (nt=32)
  mgemm256_k<1, float><<<dim3((B_/256)*(D_/256)), 512, 0, stream>>>(
      ws_h, ws_w2t, ff_b2, ws_fnb, out, B_, D_, 2048, 0.2f);

  geo_k<<<1, 1, 0, stream>>>(ws_div, ws_cen, div_w, cen_w, out + (size_t)B_ * D_);
}

// Round 11
// 399.715 us; speedup vs baseline: 1.1314x; 1.0973x over previous
//
#include <hip/hip_runtime.h>
#include <hip/hip_bf16.h>
#include <math.h>

typedef __hip_bfloat16 bf16;

#define D_  1024
#define K_  10
#define B_  16384
#define H_  8
#define HD_ 128

struct alignas(16) BF8 { bf16 v[8]; };
struct alignas(8)  BF4 { bf16 v[4]; };

typedef __bf16 bf8v __attribute__((ext_vector_type(8)));
typedef float  f4v  __attribute__((ext_vector_type(4)));

__device__ __forceinline__ float b2f(bf16 x){ return __bfloat162float(x); }
__device__ __forceinline__ bf16  f2b(float x){ return __float2bfloat16(x); }

#define GL2LDS16(g, l) __builtin_amdgcn_global_load_lds( \
    (__attribute__((address_space(1))) void*)(g), \
    (__attribute__((address_space(3))) void*)(l), 16, 0, 0)

// ---------------- row-wise L2 normalize -> bf16 ----------------------------
__global__ __launch_bounds__(256) void l2norm_k(const float* __restrict__ x,
                                                bf16* __restrict__ fnb) {
  int b = blockIdx.x, t = threadIdx.x;
  float4 v = ((const float4*)(x + (size_t)b * D_))[t];
  float p = v.x*v.x + v.y*v.y + v.z*v.z + v.w*v.w;
  #pragma unroll
  for (int o = 32; o > 0; o >>= 1) p += __shfl_down(p, o);
  __shared__ float wsum[4];
  if ((t & 63) == 0) wsum[t >> 6] = p;
  __syncthreads();
  __shared__ float inv_s;
  if (t == 0) inv_s = 1.f / fmaxf(sqrtf(wsum[0]+wsum[1]+wsum[2]+wsum[3]), 1e-8f);
  __syncthreads();
  float iv = inv_s;
  BF4 o;
  o.v[0] = f2b(v.x*iv); o.v[1] = f2b(v.y*iv);
  o.v[2] = f2b(v.z*iv); o.v[3] = f2b(v.w*iv);
  ((BF4*)(fnb + (size_t)b * D_))[t] = o;
}

// ------- merged weight transposes f32[R][C] -> bf16[C][R], 1 launch --------
__global__ __launch_bounds__(256) void wt3_k(
    const float* __restrict__ qw, const float* __restrict__ w1,
    const float* __restrict__ w2,
    bf16* __restrict__ o_qw, bf16* __restrict__ o_w1, bf16* __restrict__ o_w2) {
  __shared__ float tle[32][33];
  int b = blockIdx.x;
  const float* w; bf16* wt; int R, C, c0, r0;
  if (b < 1024)      { w = qw; wt = o_qw; R = 1024; C = 1024;
                       c0 = (b & 31) * 32;      r0 = (b >> 5) * 32; }
  else if (b < 3072) { int i = b - 1024; w = w1; wt = o_w1; R = 1024; C = 2048;
                       c0 = (i % 64) * 32;      r0 = (i / 64) * 32; }
  else               { int i = b - 3072; w = w2; wt = o_w2; R = 2048; C = 1024;
                       c0 = (i % 32) * 32;      r0 = (i / 32) * 32; }
  int tx = threadIdx.x & 31, ty = threadIdx.x >> 5;
  #pragma unroll
  for (int i = 0; i < 32; i += 8)
    tle[ty + i][tx] = w[(size_t)(r0 + ty + i) * C + c0 + tx];
  __syncthreads();
  #pragma unroll
  for (int i = 0; i < 32; i += 8)
    wt[(size_t)(c0 + ty + i) * R + r0 + tx] = f2b(tle[tx][ty + i]);
}

// ---------------- small panel GEMM: out[10][N] = act(A[10][KD] @ W + b) ----
template<int COLS, int KD, int ACT>
__global__ __launch_bounds__(256) void panelmm_k(
    const float* __restrict__ A, const float* __restrict__ W,
    const float* __restrict__ bias, const float* __restrict__ aux,
    float* __restrict__ out,
    const float* __restrict__ W2, const float* __restrict__ bias2,
    float* __restrict__ out2, int N, int npanel) {
  constexpr int GROUPS = 256 / COLS;
  constexpr int DCH = KD / GROUPS;
  __shared__ float A_s[K_][KD];
  __shared__ float part[K_][COLS][GROUPS];
  const int t = threadIdx.x;
  int blk = blockIdx.x;
  const float* Wm = W; const float* bm = bias; float* om = out;
  if (blk >= npanel) { blk -= npanel; Wm = W2; bm = bias2; om = out2; }
  const int panel = blk;
  for (int i = t; i < K_*KD; i += 256) A_s[0][i] = A[i];
  __syncthreads();
  const int cg = t % COLS, g = t / COLS;
  const int col = panel*COLS + cg;
  float s[K_];
  #pragma unroll
  for (int r = 0; r < K_; ++r) s[r] = 0.f;
  const float* wp = Wm + (size_t)(g*DCH)*N + col;
  for (int d = g*DCH; d < (g+1)*DCH; ++d) {
    float wv = *wp; wp += N;
    #pragma unroll
    for (int r = 0; r < K_; ++r) s[r] = fmaf(A_s[r][d], wv, s[r]);
  }
  #pragma unroll
  for (int r = 0; r < K_; ++r) part[r][cg][g] = s[r];
  __syncthreads();
  for (int o = t; o < K_*COLS; o += 256) {
    int r = o / COLS, c = o % COLS;
    float v = 0.f;
    #pragma unroll
    for (int gg = 0; gg < GROUPS; ++gg) v += part[r][c][gg];
    v += bm[panel*COLS + c];
    if constexpr (ACT == 1) v = fmaxf(v, 0.f);
    if constexpr (ACT == 2) v = aux[(size_t)r*N + panel*COLS + c] + 0.1f*tanhf(v);
    om[(size_t)r*N + panel*COLS + c] = v;
  }
}

// ---------------- ar3: normalize anchors + diversity loss ------------------
__global__ __launch_bounds__(256) void ar3_k(const float* __restrict__ an_un,
    float* __restrict__ an, float* __restrict__ na, float* __restrict__ divloss) {
  __shared__ float a_s[K_][D_];
  __shared__ float nrm[K_];
  __shared__ float dm[45];
  const int t = threadIdx.x;
  for (int i = t; i < K_*D_; i += 256) a_s[0][i] = an_un[i];
  __syncthreads();
  const int wid = t >> 6, lane = t & 63;
  for (int r = wid; r < K_; r += 4) {
    float p = 0.f;
    for (int j = lane; j < D_; j += 64) p += a_s[r][j]*a_s[r][j];
    #pragma unroll
    for (int o = 1; o < 64; o <<= 1) p += __shfl_xor(p, o);
    if (lane == 0) nrm[r] = p;
  }
  __syncthreads();
  for (int i = t; i < K_*D_; i += 256) {
    int r = i >> 10;
    float iv = 1.f / fmaxf(sqrtf(nrm[r]), 1e-8f);
    float v = a_s[0][i] * iv;
    a_s[0][i] = v;
    an[i] = v;
  }
  if (t < K_) {
    float iv = 1.f / fmaxf(sqrtf(nrm[t]), 1e-8f);
    na[t] = nrm[t] * iv * iv;
  }
  __syncthreads();
  const int pr = t >> 2, sub = t & 3;
  if (pr < 45) {
    int i = 0, j = 0, c = pr;
    for (i = 0; i < K_; ++i) { int cnt = K_-1-i; if (c < cnt) { j = i+1+c; break; } c -= cnt; }
    float s = 0.f;
    for (int d = sub*256; d < sub*256 + 256; ++d) {
      float df = a_s[i][d] - a_s[j][d]; s += df*df;
    }
    s += __shfl_xor(s, 1); s += __shfl_xor(s, 2);
    if (sub == 0) dm[pr] = sqrtf(fmaxf(s, 1e-24f));
  }
  __syncthreads();
  if (t == 0) {
    float m = 0.f;
    for (int p = 0; p < 45; ++p) m += dm[p];
    m *= (1.f/45.f);
    *divloss = expf(-fmaxf(m, 1e-6f));
  }
}

// -------- prep: merged {W-tilde smallmm, V-tilde smallmm, anext, sbias} ----
template<int TRANSOUT, typename TW>
__device__ __forceinline__ void smallmm_body(
    int blk, const float* __restrict__ A, const TW* __restrict__ W,
    bf16* __restrict__ outb, float scale,
    float (&A_s)[K_][128], float (&part)[K_][64][4]) {
  constexpr int COLS = 64, GROUPS = 4, DCH = 32, NW = 1024;
  const int t = threadIdx.x;
  const int h = blk & 7, panel = blk >> 3;
  for (int i = t; i < K_*128; i += 256) {
    int r = i >> 7, j = i & 127;
    A_s[r][j] = A[r*1024 + h*128 + j];
  }
  __syncthreads();
  const int cg = t % COLS, g = t / COLS;
  const int col = panel*COLS + cg;
  float s[K_];
  #pragma unroll
  for (int r = 0; r < K_; ++r) s[r] = 0.f;
  const TW* wp = W + (size_t)(h*128 + g*DCH)*NW + col;
  for (int d = 0; d < DCH; ++d) {
    float wv;
    if constexpr (sizeof(TW) == 2) wv = b2f(*wp); else wv = *wp;
    wp += NW;
    #pragma unroll
    for (int r = 0; r < K_; ++r) s[r] = fmaf(A_s[r][g*DCH + d], wv, s[r]);
  }
  #pragma unroll
  for (int r = 0; r < K_; ++r) part[r][cg][g] = s[r];
  __syncthreads();
  for (int o = t; o < 16*COLS; o += 256) {
    int r = o / COLS, c = o % COLS;
    float v = 0.f;
    if (r < K_) {
      #pragma unroll
      for (int gg = 0; gg < GROUPS; ++gg) v += part[r][c][gg];
      v *= scale;
    }
    if constexpr (TRANSOUT) outb[(size_t)(panel*COLS + c)*128 + h*16 + r] = f2b(v);
    else                    outb[(size_t)(h*16 + r)*NW + panel*COLS + c] = f2b(v);
  }
}

__global__ __launch_bounds__(256) void prep_k(
    const float* __restrict__ Km, const float* __restrict__ Vm,
    const float* __restrict__ an, const float* __restrict__ na,
    const bf16* __restrict__ wq, const float* __restrict__ ow,
    const float* __restrict__ qb,
    bf16* __restrict__ wt, bf16* __restrict__ vt, float* __restrict__ sb) {
  __shared__ float A_s[K_][128];
  __shared__ float part[K_][64][4];
  const int b = blockIdx.x;
  if (b < 128) {
    smallmm_body<0, bf16>(b, Km, wq, wt, 0.08838834764831845f, A_s, part);
  } else if (b < 256) {
    smallmm_body<1, float>(b - 128, Vm, ow, vt, 1.f, A_s, part);
  } else if (b < 384) {
    int k = b - 256;                       // W-tilde ext row 128+k = -2*an_k
    bf16* dst = wt + (size_t)(128 + k) * 1024;
    int i = threadIdx.x * 4;
    BF4 o;
    if (k < K_) {
      float4 a = *(const float4*)(an + (size_t)k*1024 + i);
      o.v[0] = f2b(-2.f*a.x); o.v[1] = f2b(-2.f*a.y);
      o.v[2] = f2b(-2.f*a.z); o.v[3] = f2b(-2.f*a.w);
    } else {
      o.v[0] = o.v[1] = o.v[2] = o.v[3] = f2b(0.f);
    }
    *(BF4*)(dst + i) = o;
  } else {
    int c = threadIdx.x;                   // sbias ext
    if (c < 128) {
      int h = c >> 4, k = c & 15;
      float s = 0.f;
      if (k < K_) {
        for (int j = 0; j < HD_; ++j)
          s = fmaf(qb[h*HD_ + j], Km[(size_t)k*D_ + h*HD_ + j], s);
      }
      sb[c] = s * 0.08838834764831845f;
    } else {
      int j = c - 128;
      sb[c] = (j < K_) ? (1.f + na[j]) : 0.f;
    }
  }
}

// ---------------- 128^2 dbuf swizzled MFMA GEMM (S-GEMM, enh-GEMM) ---------
// K templated: nt constexpr, unroll-2 makes buf static. Swizzle verified
// conflict-free (round 9: SQ_LDS_BANK_CONFLICT = 0).
template<int EPI, int KD, typename TO>
__global__ __launch_bounds__(256) void mgemm_k(
    const bf16* __restrict__ A, const bf16* __restrict__ Bt,
    const float* __restrict__ bias, const bf16* __restrict__ aux,
    TO* __restrict__ out, int M, int N, float scale) {
  constexpr int BM = 128, BN = 128, BK = 32;
  constexpr int nt = KD / BK;
  __shared__ bf16 As[2][BM*BK];
  __shared__ bf16 Bs[2][BN*BK];
  const int tid = threadIdx.x;
  const int nMB = M / BM;
  const int nwg = gridDim.x;
  int wg = blockIdx.x;
  wg = (wg & 7) * (nwg >> 3) + (wg >> 3);
  const int bm = (wg % nMB) * BM, bn = (wg / nMB) * BN;

  const int srow = tid >> 2;
  const int ssw  = (((tid & 3) ^ ((tid >> 3) & 3)) * 8);
  const bf16* gA = A  + (size_t)(bm + srow) * KD + ssw;
  const bf16* gB = Bt + (size_t)(bn + srow) * KD + ssw;
  const size_t rstep = (size_t)64 * KD;

  const int w    = tid >> 6;
  const int lane = tid & 63;
  const int wr = (w >> 1) * 64, wc = (w & 1) * 64;
  const int fr = lane & 15, fg = lane >> 4;
  const int key = (fr >> 1) & 3;
  const int co  = (fg ^ key) * 8;

  f4v acc[4][4];
  const f4v zz = {0.f, 0.f, 0.f, 0.f};
  #pragma unroll
  for (int m = 0; m < 4; ++m)
    #pragma unroll
    for (int n = 0; n < 4; ++n) acc[m][n] = zz;

  GL2LDS16(gA,         &As[0][0] + tid*8);
  GL2LDS16(gA + rstep, &As[0][0] + tid*8 + 2048);
  GL2LDS16(gB,         &Bs[0][0] + tid*8);
  GL2LDS16(gB + rstep, &Bs[0][0] + tid*8 + 2048);
  __syncthreads();

  #pragma unroll 2
  for (int t = 0; t < nt; ++t) {
    const int buf = t & 1;
    if (t + 1 < nt) {
      const int ko = (t + 1) * BK;
      GL2LDS16(gA + ko,         &As[buf^1][0] + tid*8);
      GL2LDS16(gA + rstep + ko, &As[buf^1][0] + tid*8 + 2048);
      GL2LDS16(gB + ko,         &Bs[buf^1][0] + tid*8);
      GL2LDS16(gB + rstep + ko, &Bs[buf^1][0] + tid*8 + 2048);
    }
    const bf16* la = &As[buf][0];
    const bf16* lb = &Bs[buf][0];
    bf8v af[4], bq[4];
    #pragma unroll
    for (int m = 0; m < 4; ++m)
      af[m] = *(const bf8v*)(la + (wr + m*16 + fr)*BK + co);
    #pragma unroll
    for (int n = 0; n < 4; ++n)
      bq[n] = *(const bf8v*)(lb + (wc + n*16 + fr)*BK + co);
    __builtin_amdgcn_s_setprio(1);
    #pragma unroll
    for (int m = 0; m < 4; ++m)
      #pragma unroll
      for (int n = 0; n < 4; ++n)
        acc[m][n] = __builtin_amdgcn_mfma_f32_16x16x32_bf16(af[m], bq[n], acc[m][n], 0, 0, 0);
    __builtin_amdgcn_s_setprio(0);
    __syncthreads();
  }

  float bv[4];
  #pragma unroll
  for (int n = 0; n < 4; ++n) bv[n] = bias[bn + wc + n*16 + fr];
  #pragma unroll
  for (int m = 0; m < 4; ++m) {
    #pragma unroll
    for (int r = 0; r < 4; ++r) {
      const int row = bm + wr + m*16 + fg*4 + r;
      #pragma unroll
      for (int n = 0; n < 4; ++n) {
        const int col = bn + wc + n*16 + fr;
        float x = acc[m][n][r] + bv[n];
        if constexpr (EPI == 1) x = b2f(aux[(size_t)row * N + col]) + scale * x;
        if constexpr (EPI == 2) x = 0.5f * x * (1.f + erff(x * 0.70710678118654752f));
        if constexpr (sizeof(TO) == 2) out[(size_t)row * N + col] = f2b(x);
        else                           out[(size_t)row * N + col] = x;
      }
    }
  }
}

// ---------------- 256^2 2-phase BK=64 MFMA GEMM (round-8 proven) -----------
// dbuf, stage-next-before-compute, one __syncthreads per K-tile, both-sides
// swizzle (conflict-free, measured 0), setprio, XCD swizzle. K templated.
template<int EPI, int KD, typename TO>
__global__ __launch_bounds__(512) void mgemm256_k(
    const bf16* __restrict__ A, const bf16* __restrict__ Bt,
    const float* __restrict__ bias, const bf16* __restrict__ aux,
    TO* __restrict__ out, int M, int N, float scale) {
  constexpr int BM = 256, BN = 256, BK = 64;
  constexpr int nt = KD / BK;
  __shared__ bf16 As[2][BM*BK];   // 2 x 32 KB
  __shared__ bf16 Bs[2][BN*BK];   // 2 x 32 KB -> 128 KB
  const int tid = threadIdx.x;
  const int nMB = M / BM;
  const int nwg = gridDim.x;
  int wg = blockIdx.x;
  wg = (wg & 7) * (nwg >> 3) + (wg >> 3);   // XCD swizzle (nwg % 8 == 0)
  const int bm = (wg % nMB) * BM, bn = (wg / nMB) * BN;

  const int srow = tid >> 3;
  const int scsw = ((tid & 7) ^ (srow & 7)) * 8;    // pre-swizzled source
  const bf16* gA = A  + (size_t)(bm + srow) * KD + scsw;
  const bf16* gB = Bt + (size_t)(bn + srow) * KD + scsw;
  const size_t lstep = (size_t)64 * KD;

  const int wid = tid >> 6, lane = tid & 63;
  const int wm = wid >> 2, wn = wid & 3;            // 2M x 4N waves
  const int fr = lane & 15, fg = lane >> 4;
  const int fsw = fr & 7;
  const int c0 = ((fg     ^ fsw) * 8);
  const int c1 = (((4+fg) ^ fsw) * 8);

  f4v acc[8][4];
  const f4v zz = {0.f, 0.f, 0.f, 0.f};
  #pragma unroll
  for (int m = 0; m < 8; ++m)
    #pragma unroll
    for (int n = 0; n < 4; ++n) acc[m][n] = zz;

  // prologue: stage tile 0 into buf 0
  #pragma unroll
  for (int l = 0; l < 4; ++l) {
    GL2LDS16(gA + l*lstep, &As[0][0] + tid*8 + l*4096);
    GL2LDS16(gB + l*lstep, &Bs[0][0] + tid*8 + l*4096);
  }
  __syncthreads();

  #pragma unroll 2
  for (int t = 0; t < nt; ++t) {
    const int buf = t & 1;
    if (t + 1 < nt) {                       // stage next tile (flies under MFMA)
      const int ko = (t + 1) * BK;
      #pragma unroll
      for (int l = 0; l < 4; ++l) {
        GL2LDS16(gA + l*lstep + ko, &As[buf^1][0] + tid*8 + l*4096);
        GL2LDS16(gB + l*lstep + ko, &Bs[buf^1][0] + tid*8 + l*4096);
      }
    }
    const bf16* la = &As[buf][0];
    const bf16* lb = &Bs[buf][0];
    bf8v bq[8];
    #pragma unroll
    for (int n = 0; n < 4; ++n) {
      const int rb = wn*64 + n*16 + fr;
      bq[n*2]   = *(const bf8v*)(lb + rb*64 + c0);
      bq[n*2+1] = *(const bf8v*)(lb + rb*64 + c1);
    }
    __builtin_amdgcn_s_setprio(1);
    #pragma unroll
    for (int m = 0; m < 8; ++m) {
      const int ra = wm*128 + m*16 + fr;
      bf8v a0 = *(const bf8v*)(la + ra*64 + c0);
      bf8v a1 = *(const bf8v*)(la + ra*64 + c1);
      #pragma unroll
      for (int n = 0; n < 4; ++n) {
        acc[m][n] = __builtin_amdgcn_mfma_f32_16x16x32_bf16(a0, bq[n*2],   acc[m][n], 0, 0, 0);
        acc[m][n] = __builtin_amdgcn_mfma_f32_16x16x32_bf16(a1, bq[n*2+1], acc[m][n], 0, 0, 0);
      }
    }
    __builtin_amdgcn_s_setprio(0);
    __syncthreads();
  }

  float bv[4];
  #pragma unroll
  for (int n = 0; n < 4; ++n) bv[n] = bias[bn + wn*64 + n*16 + fr];
  #pragma unroll
  for (int m = 0; m < 8; ++m) {
    #pragma unroll
    for (int r = 0; r < 4; ++r) {
      const int row = bm + wm*128 + m*16 + fg*4 + r;
      #pragma unroll
      for (int n = 0; n < 4; ++n) {
        const int col = bn + wn*64 + n*16 + fr;
        float x = acc[m][n][r] + bv[n];
        if constexpr (EPI == 1) x = b2f(aux[(size_t)row * N + col]) + scale * x;
        if constexpr (EPI == 2) x = 0.5f * x * (1.f + erff(x * 0.70710678118654752f));
        if constexpr (sizeof(TO) == 2) out[(size_t)row * N + col] = f2b(x);
        else                           out[(size_t)row * N + col] = x;
      }
    }
  }
}

// ---------------- attn2: softmax(S) -> aw; center loss from S d2 cols ------
__global__ __launch_bounds__(256) void attn2_k(
    const float* __restrict__ S, bf16* __restrict__ awp,
    float* __restrict__ cen_acc) {
  __shared__ float cred[4];
  const int t = threadIdx.x;
  const int wid = t >> 6, lane = t & 63;
  const int sub = lane & 7, head = lane >> 3;
  const int k0 = sub*2, k1 = k0 + 1;
  float c_acc = 0.f;
  const int row0 = blockIdx.x * 32 + wid * 8;

  for (int i = 0; i < 8; ++i) {
    const int row = row0 + i;
    const float* Sr = S + (size_t)row * 256;
    float2 sv = *(const float2*)(Sr + head*16 + k0);
    float v0 = (k0 < K_) ? sv.x : -1e30f;
    float v1 = (k1 < K_) ? sv.y : -1e30f;
    float m = fmaxf(v0, v1);
    m = fmaxf(m, __shfl_xor(m,1)); m = fmaxf(m, __shfl_xor(m,2)); m = fmaxf(m, __shfl_xor(m,4));
    float e0 = (k0 < K_) ? __expf(v0 - m) : 0.f;
    float e1 = (k1 < K_) ? __expf(v1 - m) : 0.f;
    float es = e0 + e1;
    es += __shfl_xor(es,1); es += __shfl_xor(es,2); es += __shfl_xor(es,4);
    float inv = 1.f / es;
    float a0 = e0 * inv, a1 = e1 * inv;
    bf16 b0 = f2b(a0), b1 = f2b(a1);
    unsigned int pk = (unsigned int)(*(unsigned short*)&b0)
                    | ((unsigned int)(*(unsigned short*)&b1) << 16);
    *(unsigned int*)(awp + (size_t)row*128 + head*16 + k0) = pk;
    float g0 = a0, g1 = a1;
    g0 += __shfl_xor(g0,8); g0 += __shfl_xor(g0,16); g0 += __shfl_xor(g0,32);
    g1 += __shfl_xor(g1,8); g1 += __shfl_xor(g1,16); g1 += __shfl_xor(g1,32);
    if (sub < 5) {
      float d20 = Sr[128 + k0];
      float d21 = Sr[128 + k1];
      c_acc = fmaf(g0, sqrtf(fmaxf(d20, 1e-12f)), c_acc);
      c_acc = fmaf(g1, sqrtf(fmaxf(d21, 1e-12f)), c_acc);
    }
  }
  #pragma unroll
  for (int o = 1; o < 64; o <<= 1) c_acc += __shfl_xor(c_acc, o);
  if (lane == 0) cred[wid] = c_acc;
  __syncthreads();
  if (t == 0) {
    float s = (cred[0]+cred[1]+cred[2]+cred[3]) * (1.f/64.f/(float)B_);
    atomicAdd(cen_acc, s);
  }
}

// ---------------- LayerNorm over rows of bf16 ------------------------------
__global__ __launch_bounds__(256) void ln_k(const bf16* __restrict__ x,
    const float* __restrict__ g, const float* __restrict__ bta,
    bf16* __restrict__ out) {
  int b = blockIdx.x, t = threadIdx.x;
  BF4 ld = ((const BF4*)(x + (size_t)b * D_))[t];
  float v[4];
  #pragma unroll
  for (int j = 0; j < 4; ++j) v[j] = b2f(ld.v[j]);
  float s = v[0]+v[1]+v[2]+v[3];
  #pragma unroll
  for (int o = 32; o > 0; o >>= 1) s += __shfl_down(s, o);
  __shared__ float w1[4], w2[4];
  if ((t & 63) == 0) w1[t >> 6] = s;
  __syncthreads();
  __shared__ float mu_s, rs_s;
  if (t == 0) mu_s = (w1[0]+w1[1]+w1[2]+w1[3]) * (1.f/D_);
  __syncthreads();
  float mu = mu_s;
  float qv = 0.f;
  #pragma unroll
  for (int j = 0; j < 4; ++j) { float d = v[j]-mu; qv += d*d; }
  #pragma unroll
  for (int o = 32; o > 0; o >>= 1) qv += __shfl_down(qv, o);
  if ((t & 63) == 0) w2[t >> 6] = qv;
  __syncthreads();
  if (t == 0) rs_s = rsqrtf((w2[0]+w2[1]+w2[2]+w2[3]) * (1.f/D_) + 1e-5f);
  __syncthreads();
  float rs = rs_s;
  BF4 o;
  #pragma unroll
  for (int j = 0; j < 4; ++j) {
    int col = t*4 + j;
    o.v[j] = f2b((v[j]-mu)*rs*g[col] + bta[col]);
  }
  ((BF4*)(out + (size_t)b * D_))[t] = o;
}

// ---------------- final scalar geo -----------------------------------------
__global__ void geo_k(const float* __restrict__ divl, const float* __restrict__ cen,
                      const float* __restrict__ div_w, const float* __restrict__ cen_w,
                      float* __restrict__ out) {
  float g = fabsf(*div_w) * (*divl) + fabsf(*cen_w) * (*cen);
  out[0] = fminf(fmaxf(g, 0.f), 0.01f);
}

extern "C" void kernel_launch(void* const* d_in, const int* in_sizes, int n_in,
                              void* d_out, int out_size, void* d_ws, size_t ws_size,
                              hipStream_t stream) {
  const float* features = (const float*)d_in[0];
  const float* anchors  = (const float*)d_in[1];
  const float* ar_w1 = (const float*)d_in[2];
  const float* ar_b1 = (const float*)d_in[3];
  const float* ar_w2 = (const float*)d_in[4];
  const float* ar_b2 = (const float*)d_in[5];
  const float* q_w = (const float*)d_in[6];
  const float* q_b = (const float*)d_in[7];
  const float* k_w = (const float*)d_in[8];
  const float* k_b = (const float*)d_in[9];
  const float* v_w = (const float*)d_in[10];
  const float* v_b = (const float*)d_in[11];
  const float* o_w = (const float*)d_in[12];
  const float* o_b = (const float*)d_in[13];
  const float* ln_g = (const float*)d_in[14];
  const float* ln_b = (const float*)d_in[15];
  const float* ff_w1 = (const float*)d_in[16];
  const float* ff_b1 = (const float*)d_in[17];
  const float* ff_w2 = (const float*)d_in[18];
  const float* ff_b2 = (const float*)d_in[19];
  const float* div_w = (const float*)d_in[20];
  const float* cen_w = (const float*)d_in[21];
  float* out = (float*)d_out;

  char* w = (char*)d_ws;
  bf16* ws_fnb = (bf16*)w;  w += (size_t)B_ * D_ * 2;
  bf16* ws_enh = (bf16*)w;  w += (size_t)B_ * D_ * 2;
  bf16* ws_ln  = (bf16*)w;  w += (size_t)B_ * D_ * 2;
  bf16* ws_h   = (bf16*)w;  w += (size_t)B_ * 2048 * 2;
  float* ws_S  = (float*)w; w += (size_t)B_ * 256 * 4;
  bf16* ws_awp = (bf16*)w;  w += (size_t)B_ * 128 * 2;
  bf16* ws_wq  = (bf16*)w;  w += (size_t)D_ * D_ * 2;
  bf16* ws_w1t = (bf16*)w;  w += (size_t)D_ * 2048 * 2;
  bf16* ws_w2t = (bf16*)w;  w += (size_t)2048 * D_ * 2;
  bf16* ws_wt  = (bf16*)w;  w += (size_t)256 * D_ * 2;   // W-tilde ext [256][1024]
  bf16* ws_vt  = (bf16*)w;  w += (size_t)D_ * 128 * 2;   // V-tilde^T [1024][128]
  float* ws_har = (float*)w;  w += (size_t)K_ * (D_/2) * 4;
  float* ws_anu = (float*)w;  w += (size_t)K_ * D_ * 4;
  float* ws_an  = (float*)w;  w += (size_t)K_ * D_ * 4;
  float* ws_k   = (float*)w;  w += (size_t)K_ * D_ * 4;
  float* ws_v   = (float*)w;  w += (size_t)K_ * D_ * 4;
  float* ws_na  = (float*)w;  w += 256;
  float* ws_div = (float*)w;  w += 256;
  float* ws_cen = (float*)w;  w += 256;
  float* ws_sb  = (float*)w;  w += 512;
  if ((size_t)(w - (char*)d_ws) > ws_size) return;

  hipMemsetAsync(ws_cen, 0, 4, stream);

  // merged weight transposes (1 launch)
  wt3_k<<<5120, 256, 0, stream>>>(q_w, ff_w1, ff_w2, ws_wq, ws_w1t, ws_w2t);

  l2norm_k<<<B_, 256, 0, stream>>>(features, ws_fnb);

  panelmm_k<32, 1024, 1><<<16, 256, 0, stream>>>(
      anchors, ar_w1, ar_b1, nullptr, ws_har,
      nullptr, nullptr, nullptr, D_/2, 16);
  panelmm_k<64, 512, 2><<<16, 256, 0, stream>>>(
      ws_har, ar_w2, ar_b2, anchors, ws_anu,
      nullptr, nullptr, nullptr, D_, 16);
  ar3_k<<<1, 256, 0, stream>>>(ws_anu, ws_an, ws_na, ws_div);
  panelmm_k<64, 1024, 0><<<32, 256, 0, stream>>>(
      ws_an, k_w, k_b, nullptr, ws_k,
      v_w, v_b, ws_v, D_, 16);

  // merged {W-tilde, V-tilde, anext, sbias} (1 launch)
  prep_k<<<385, 256, 0, stream>>>(ws_k, ws_v, ws_an, ws_na,
                                  ws_wq, o_w, q_b, ws_wt, ws_vt, ws_sb);

  // S = fn @ [W-tilde | -2an^T] + [sb | 1+na]   [B,256] f32
  mgemm_k<0, 1024, float><<<dim3((B_/128)*(256/128)), 256, 0, stream>>>(
      ws_fnb, ws_wt, ws_sb, nullptr, ws_S, B_, 256, 0.f);

  attn2_k<<<B_/32, 256, 0, stream>>>(ws_S, ws_awp, ws_cen);

  // enh = fn + 0.1*(awp @ V-tilde + o_b)
  mgemm_k<1, 128, bf16><<<dim3((B_/128)*(D_/128)), 256, 0, stream>>>(
      ws_awp, ws_vt, o_b, ws_fnb, ws_enh, B_, D_, 0.1f);

  ln_k<<<B_, 256, 0, stream>>>(ws_enh, ln_g, ln_b, ws_ln);

  // h = gelu(ln @ ff_w1 + ff_b1)
  mgemm256_k<2, 1024, bf16><<<dim3((B_/256)*(2048/256)), 512, 0, stream>>>(
      ws_ln, ws_w1t, ff_b1, nullptr, ws_h, B_, 2048, 0.f);

  // final = fn + 0.2*(h @ ff_w2 + ff_b2) -> d_out (f32)
  mgemm256_k<1, 2048, float><<<dim3((B_/256)*(D_/256)), 512, 0, stream>>>(
      ws_h, ws_w2t, ff_b2, ws_fnb, out, B_, D_, 0.2f);

  geo_k<<<1, 1, 0, stream>>>(ws_div, ws_cen, div_w, cen_w, out + (size_t)B_ * D_);
}